// Round 6
// baseline (180.249 us; speedup 1.0000x reference)
//
#include <hip/hip_runtime.h>

#define NG 256
#define NG2 (NG*NG)

// gather tiling
#define TI 8            // cell rows per tile
#define TJ 4            // cell cols per tile
#define NTILES ((NG/TI)*(NG/TJ))   // 32*64 = 2048
#define CAP 2048        // record capacity per tile
#define RSTRIDE 9       // LDS floats per record (8 data + 1 pad for bank spread)

constexpr float DX      = 1.0f / 256.0f;
constexpr float INV_DX  = 256.0f;
constexpr float DT      = 2e-5f;
constexpr float P_VOL   = (1.0f/512.0f) * (1.0f/512.0f);
constexpr float P_MASS  = P_VOL;           // rho = 1
constexpr float MU_0    = 1000.0f / (2.0f * 1.2f);            // E/(2(1+nu))
constexpr float LAM_0   = 1000.0f * 0.2f / (1.2f * 0.6f);     // E nu/((1+nu)(1-2nu))
constexpr float GRAV    = 50.0f;

__device__ __forceinline__ int bin_of(float px, float py) {
    int bx = (int)floorf(px * INV_DX - 0.5f);
    int by = (int)floorf(py * INV_DX - 0.5f);
    bx = min(max(bx, 0), NG - 1);
    by = min(max(by, 0), NG - 1);
    return (bx << 8) | by;
}

// quadratic B-spline weight as a function of (node - particle) distance in cells
__device__ __forceinline__ float bw(float t) {
    float at = fabsf(t);
    float a  = fmaxf(1.5f - at, 0.0f);
    float w1 = 0.75f - t * t;
    float w2 = 0.5f * a * a;
    return (at < 0.5f) ? w1 : w2;
}

// ---------------- binning + scan ----------------

__global__ __launch_bounds__(256) void binrank_kernel(
    const float* __restrict__ x, int* __restrict__ counts, int* __restrict__ rank, int n)
{
    int i = blockIdx.x * blockDim.x + threadIdx.x;
    if (i >= n) return;
    float2 p = ((const float2*)x)[i];
    int b = bin_of(p.x, p.y);
    rank[i] = atomicAdd(&counts[b], 1);
}

__global__ __launch_bounds__(256) void scan1_kernel(
    const int* __restrict__ counts, int* __restrict__ starts, int* __restrict__ bsum)
{
    __shared__ int tmp[256];
    int t = threadIdx.x, b = blockIdx.x;
    int v = counts[b * 256 + t];
    tmp[t] = v;
    __syncthreads();
    #pragma unroll
    for (int off = 1; off < 256; off <<= 1) {
        int add = (t >= off) ? tmp[t - off] : 0;
        __syncthreads();
        tmp[t] += add;
        __syncthreads();
    }
    starts[b * 256 + t] = tmp[t] - v;          // exclusive within block
    if (t == 255) bsum[b] = tmp[255];          // block total
}

__global__ __launch_bounds__(256) void scan2_kernel(int* __restrict__ bsum)
{
    __shared__ int tmp[256];
    int t = threadIdx.x;
    int v = bsum[t];
    tmp[t] = v;
    __syncthreads();
    #pragma unroll
    for (int off = 1; off < 256; off <<= 1) {
        int add = (t >= off) ? tmp[t - off] : 0;
        __syncthreads();
        tmp[t] += add;
        __syncthreads();
    }
    bsum[t] = tmp[t] - v;                      // exclusive
}

__global__ __launch_bounds__(256) void scan3_kernel(
    int* __restrict__ starts, const int* __restrict__ bsum, int n)
{
    int i = blockIdx.x * blockDim.x + threadIdx.x;
    if (i < NG2) starts[i] += bsum[i >> 8];
    if (i == 0) starts[NG2] = n;
}

// ---------------- particle update: coalesced payload + 4B perm scatter ----------------

__global__ __launch_bounds__(256) void compute_kernel(
    const float* __restrict__ x, const float* __restrict__ v,
    const float* __restrict__ C, const float* __restrict__ F,
    const int* __restrict__ mat, const float* __restrict__ Jp,
    const int* __restrict__ starts, const int* __restrict__ rank,
    float4* __restrict__ payload0, float4* __restrict__ payload1,
    int* __restrict__ perm,
    float4* __restrict__ F_out4, float* __restrict__ mat_out, float* __restrict__ Jp_out,
    int n)
{
    int i = blockIdx.x * blockDim.x + threadIdx.x;
    if (i >= n) return;

    float2 xp = ((const float2*)x)[i];
    float2 vp = ((const float2*)v)[i];
    float4 Cp = ((const float4*)C)[i];
    float4 Fp = ((const float4*)F)[i];
    int    m  = mat[i];
    float  jp = Jp[i];

    float px = xp.x, py = xp.y;
    float C00 = Cp.x, C01 = Cp.y, C10 = Cp.z, C11 = Cp.w;
    float a = Fp.x, b = Fp.y, c = Fp.z, d = Fp.w;

    // F += dt * C @ F
    float na = a + DT*(C00*a + C01*c);
    float nb = b + DT*(C00*b + C01*d);
    float nc = c + DT*(C10*a + C11*c);
    float nd = d + DT*(C10*b + C11*d);
    a = na; b = nb; c = nc; d = nd;

    float h = expf(10.0f * (1.0f - jp));
    if (m == 1) h = 0.3f;
    float mu  = (m == 0) ? 0.0f : MU_0 * h;
    float lam = LAM_0 * h;

    // closed-form 2x2 SVD via eigendecomposition of A^T A
    float S00 = a*a + c*c, S01 = a*b + c*d, S11 = b*b + d*d;
    float mh = 0.5f*(S00 + S11), dh = 0.5f*(S00 - S11);
    float delta = sqrtf(dh*dh + S01*S01);
    float sig1 = sqrtf(fmaxf(mh + delta, 0.0f));
    float sig2 = sqrtf(fmaxf(mh - delta, 0.0f));
    float e0, e1;
    if (dh >= 0.0f) { e0 = delta + dh; e1 = S01; }
    else            { e0 = S01;        e1 = delta - dh; }
    float elen = sqrtf(e0*e0 + e1*e1);
    float vc, vs;
    if (elen > 1e-30f) { float il = 1.0f/elen; vc = e0*il; vs = e1*il; }
    else               { vc = 1.0f; vs = 0.0f; }
    float inv1 = 1.0f / fmaxf(sig1, 1e-30f);
    float inv2 = 1.0f / fmaxf(sig2, 1e-30f);
    float u1x = ( a*vc + b*vs) * inv1, u1y = ( c*vc + d*vs) * inv1;
    float u2x = (-a*vs + b*vc) * inv2, u2y = (-c*vs + d*vc) * inv2;

    if (m == 2) {   // snow plasticity
        float c1 = fminf(fmaxf(sig1, 1.0f - 2.5e-2f), 1.0f + 4.5e-3f);
        float c2 = fminf(fmaxf(sig2, 1.0f - 2.5e-2f), 1.0f + 4.5e-3f);
        jp = jp * (sig1 / c1) * (sig2 / c2);
        sig1 = c1; sig2 = c2;
    }
    float J = sig1 * sig2;

    if (m == 0) {              // fluid: F = sqrt(J) I
        float s = sqrtf(J);
        a = s; b = 0.0f; c = 0.0f; d = s;
    } else if (m == 2) {       // snow: F = U diag(sig) Vh
        a = sig1*u1x*vc - sig2*u2x*vs;
        b = sig1*u1x*vs + sig2*u2x*vc;
        c = sig1*u1y*vc - sig2*u2y*vs;
        d = sig1*u1y*vs + sig2*u2y*vc;
    }
    float R00 = u1x*vc - u2x*vs, R01 = u1x*vs + u2x*vc;
    float R10 = u1y*vc - u2y*vs, R11 = u1y*vs + u2y*vc;

    float k2mu = 2.0f * mu;
    float fr00 = a - R00, fr01 = b - R01, fr10 = c - R10, fr11 = d - R11;
    float ljj  = lam * J * (J - 1.0f);
    float st00 = k2mu*(fr00*a + fr01*b) + ljj;
    float st01 = k2mu*(fr00*c + fr01*d);
    float st10 = k2mu*(fr10*a + fr11*b);
    float st11 = k2mu*(fr10*c + fr11*d) + ljj;
    const float coef = -DT * P_VOL * 4.0f * INV_DX * INV_DX;
    float A00 = coef*st00 + P_MASS*C00;
    float A01 = coef*st01 + P_MASS*C01;
    float A10 = coef*st10 + P_MASS*C10;
    float A11 = coef*st11 + P_MASS*C11;

    float bx_ = P_MASS*vp.x - (A00*px + A01*py);
    float by_ = P_MASS*vp.y - (A10*px + A11*py);

    // coalesced payload at particle order
    payload0[i] = make_float4(px * INV_DX, py * INV_DX, bx_, by_);
    payload1[i] = make_float4(A00, A01, A10, A11);

    // 4B scatter: sorted-slot -> particle index
    int sidx = starts[bin_of(px, py)] + rank[i];
    perm[sidx] = i;

    F_out4[i]  = make_float4(a, b, c, d);
    mat_out[i] = (float)m;
    Jp_out[i]  = jp;
}

// ---------------- tiled gather with LDS staging ----------------
// Block = 8x4 cell tile (32 cells x 8 slices = 256 threads). Bulk-loads the
// 10x6 bin region's records (via perm indirection) into LDS, then each cell
// accumulates its 3x3-bin stencil from LDS. Fused grid ops on the way out.

__global__ __launch_bounds__(256) void gather_tile_kernel(
    const float4* __restrict__ payload0, const float4* __restrict__ payload1,
    const int* __restrict__ perm, const int* __restrict__ starts,
    float2* __restrict__ gv)
{
    __shared__ float lds[CAP * RSTRIDE];     // 2048*9*4 = 72KB
    __shared__ int stable[10][7];            // col boundaries per bin row
    __shared__ int rowbase[10];              // LDS record base per bin row
    __shared__ int total_s;

    // bijective XCD swizzle (NTILES = 2048, 2048 % 8 == 0)
    int bid = blockIdx.x;
    int swz = (bid & 7) * (NTILES / 8) + (bid >> 3);
    int ti = swz >> 6;           // 0..31 tile row
    int tj = swz & 63;           // 0..63 tile col
    int t  = threadIdx.x;

    int r0 = ti * TI;            // first cell row of tile
    int c0 = tj * TJ;            // first cell col of tile

    // stable[r][u] = starts[(r0-2+r)*NG + clamp(c0-2+u,0..)] ; flat index up to
    // NG2 (sentinel) is valid because starts is a flat scan over all bins.
    if (t < 70) {
        int r = t / 7, u = t % 7;
        int br = r0 - 2 + r;
        int col = c0 - 2 + u;
        int val = 0;
        if (br >= 0 && br < NG) {
            int cc = col < 0 ? 0 : col;      // col <= 256 -> flat ok
            val = starts[br * NG + cc];
        }
        stable[r][u] = val;
    }
    __syncthreads();
    if (t == 0) {
        int run = 0;
        #pragma unroll
        for (int r = 0; r < 10; ++r) {
            rowbase[r] = run;
            run += stable[r][6] - stable[r][0];
        }
        total_s = run;
    }
    __syncthreads();
    bool use_lds = (total_s <= CAP);         // block-uniform

    if (use_lds) {
        #pragma unroll 1
        for (int r = 0; r < 10; ++r) {
            int s = stable[r][0], e = stable[r][6];
            int base = rowbase[r];
            for (int k = s + t; k < e; k += 256) {
                int i = perm[k];
                float4 p0 = payload0[i];
                float4 p1 = payload1[i];
                int slot = (base + (k - s)) * RSTRIDE;
                lds[slot+0] = p0.x; lds[slot+1] = p0.y;
                lds[slot+2] = p0.z; lds[slot+3] = p0.w;
                lds[slot+4] = p1.x; lds[slot+5] = p1.y;
                lds[slot+6] = p1.z; lds[slot+7] = p1.w;
            }
        }
        __syncthreads();
    }

    int cell  = t >> 3;          // 0..31
    int slice = t & 7;
    int ci = cell >> 2;          // 0..7
    int cj = cell & 3;           // 0..3
    int gi = r0 + ci, gj = c0 + cj;
    float fgi = (float)gi, fgj = (float)gj;
    float posx = fgi * DX, posy = fgj * DX;
    float msum = 0.0f, mvx = 0.0f, mvy = 0.0f;

    #pragma unroll
    for (int dr = 0; dr < 3; ++dr) {
        int r = ci + dr;                     // bin row index within tile region
        int a = stable[r][cj];               // starts[br, gj-2 clamped]
        int b = stable[r][cj + 3];           // starts[br, gj+1]
        if (use_lds) {
            int base = rowbase[r] - stable[r][0];
            for (int k = a + slice; k < b; k += 8) {
                const float* rec = &lds[(base + k) * RSTRIDE];
                float w = bw(rec[0] - fgi) * bw(rec[1] - fgj);
                msum += w;
                mvx  += w * (rec[2] + rec[4] * posx + rec[5] * posy);
                mvy  += w * (rec[3] + rec[6] * posx + rec[7] * posy);
            }
        } else {
            for (int k = a + slice; k < b; k += 8) {
                int i = perm[k];
                float4 p0 = payload0[i];
                float4 p1 = payload1[i];
                float w = bw(p0.x - fgi) * bw(p0.y - fgj);
                msum += w;
                mvx  += w * (p0.z + p1.x * posx + p1.y * posy);
                mvy  += w * (p0.w + p1.z * posx + p1.w * posy);
            }
        }
    }

    // reduce across the 8 slices (lanes differing in bits 0..2)
    #pragma unroll
    for (int off = 1; off < 8; off <<= 1) {
        msum += __shfl_xor(msum, off);
        mvx  += __shfl_xor(mvx,  off);
        mvy  += __shfl_xor(mvy,  off);
    }

    if (slice == 0) {
        float mass = msum * P_MASS;
        float vx = mvx, vy = mvy;
        if (mass > 0.0f) {
            float im = 1.0f / fmaxf(mass, 1e-12f);
            vx *= im; vy *= im;
        }
        vy -= DT * GRAV;
        if (gi < 3)       vx = fmaxf(vx, 0.0f);
        if (gi >= NG-2)   vx = fminf(vx, 0.0f);
        if (gj < 3)       vy = fmaxf(vy, 0.0f);
        if (gj >= NG-2)   vy = fminf(vy, 0.0f);
        gv[gi * NG + gj] = make_float2(vx, vy);
    }
}

__global__ __launch_bounds__(256) void g2p_kernel(
    const float* __restrict__ x, const float2* __restrict__ gv,
    float* __restrict__ x_out, float* __restrict__ v_out, float* __restrict__ C_out,
    int n)
{
    int i = blockIdx.x * blockDim.x + threadIdx.x;
    if (i >= n) return;

    float2 xp = ((const float2*)x)[i];
    float px = xp.x, py = xp.y;
    float bxf = floorf(px * INV_DX - 0.5f), byf = floorf(py * INV_DX - 0.5f);
    float fx = px * INV_DX - bxf, fy = py * INV_DX - byf;
    float wxs[3] = { 0.5f*(1.5f-fx)*(1.5f-fx), 0.75f-(fx-1.0f)*(fx-1.0f), 0.5f*(fx-0.5f)*(fx-0.5f) };
    float wys[3] = { 0.5f*(1.5f-fy)*(1.5f-fy), 0.75f-(fy-1.0f)*(fy-1.0f), 0.5f*(fy-0.5f)*(fy-0.5f) };
    int bix = (int)bxf, biy = (int)byf;

    float nvx = 0.0f, nvy = 0.0f;
    float c00 = 0.0f, c01 = 0.0f, c10 = 0.0f, c11 = 0.0f;
    #pragma unroll
    for (int ii = 0; ii < 3; ++ii) {
        float posx = (bxf + (float)ii) * DX;
        int rowbase = (bix + ii) * NG + biy;
        #pragma unroll
        for (int jj = 0; jj < 3; ++jj) {
            float w = wxs[ii] * wys[jj];
            float posy = (byf + (float)jj) * DX;
            float2 g = gv[rowbase + jj];
            nvx += w * g.x; nvy += w * g.y;
            c00 += w * g.x * posx; c01 += w * g.x * posy;
            c10 += w * g.y * posx; c11 += w * g.y * posy;
        }
    }
    const float K = 4.0f * INV_DX * INV_DX;
    c00 = (c00 - nvx * px) * K; c01 = (c01 - nvx * py) * K;
    c10 = (c10 - nvy * px) * K; c11 = (c11 - nvy * py) * K;

    ((float2*)x_out)[i] = make_float2(px + DT * nvx, py + DT * nvy);
    ((float2*)v_out)[i] = make_float2(nvx, nvy);
    ((float4*)C_out)[i] = make_float4(c00, c01, c10, c11);
}

extern "C" void kernel_launch(void* const* d_in, const int* in_sizes, int n_in,
                              void* d_out, int out_size, void* d_ws, size_t ws_size,
                              hipStream_t stream) {
    const float* x   = (const float*)d_in[0];
    const float* v   = (const float*)d_in[1];
    const float* C   = (const float*)d_in[2];
    const float* F   = (const float*)d_in[3];
    const int*   mat = (const int*)d_in[4];
    const float* Jp  = (const float*)d_in[5];

    int n = in_sizes[0] / 2;

    float* out     = (float*)d_out;
    float* x_out   = out;
    float* v_out   = out + (size_t)2*n;
    float* C_out   = out + (size_t)4*n;
    float* F_out   = out + (size_t)8*n;
    float* mat_out = out + (size_t)12*n;
    float* Jp_out  = out + (size_t)13*n;

    // payload buffers live in d_out regions that are only written by g2p at
    // the very end: payload0 -> [0,4n) floats (x_out+v_out), payload1 ->
    // [4n,8n) floats (C_out). compute writes them; gather consumes them; then
    // g2p overwrites with the real outputs. Deterministic within each call.
    float4* payload0 = (float4*)out;
    float4* payload1 = (float4*)(out + (size_t)4*n);

    int blocks = (n + 255) / 256;

    // workspace layout (small now: ~9.3 MB)
    char* ws = (char*)d_ws;
    size_t off = 0;
    int* counts = (int*)(ws + off); off += (size_t)NG2 * 4;
    int* starts = (int*)(ws + off); off += (size_t)(NG2 + 1) * 4;
    int* bsum   = (int*)(ws + off); off += 256 * 4;
    int* rank   = (int*)(ws + off); off += (size_t)n * 4;
    int* perm   = (int*)(ws + off); off += (size_t)n * 4;
    off = (off + 15) & ~(size_t)15;
    float2* gv  = (float2*)(ws + off); off += (size_t)NG2 * 8;

    hipMemsetAsync(counts, 0, (size_t)NG2 * 4, stream);
    binrank_kernel<<<blocks, 256, 0, stream>>>(x, counts, rank, n);
    scan1_kernel<<<NG2/256, 256, 0, stream>>>(counts, starts, bsum);
    scan2_kernel<<<1, 256, 0, stream>>>(bsum);
    scan3_kernel<<<NG2/256, 256, 0, stream>>>(starts, bsum, n);
    compute_kernel<<<blocks, 256, 0, stream>>>(x, v, C, F, mat, Jp,
                                               starts, rank,
                                               payload0, payload1, perm,
                                               (float4*)F_out, mat_out, Jp_out, n);
    gather_tile_kernel<<<NTILES, 256, 0, stream>>>(payload0, payload1, perm, starts, gv);
    g2p_kernel<<<blocks, 256, 0, stream>>>(x, gv, x_out, v_out, C_out, n);
}

// Round 8
// 179.659 us; speedup vs baseline: 1.0033x; 1.0033x over previous
//
#include <hip/hip_runtime.h>

#define NG 256
#define NG2 (NG*NG)

typedef float vfloat4 __attribute__((ext_vector_type(4)));   // native vector for NT stores

constexpr float DX      = 1.0f / 256.0f;
constexpr float INV_DX  = 256.0f;
constexpr float DT      = 2e-5f;
constexpr float P_VOL   = (1.0f/512.0f) * (1.0f/512.0f);
constexpr float P_MASS  = P_VOL;           // rho = 1
constexpr float MU_0    = 1000.0f / (2.0f * 1.2f);            // E/(2(1+nu))
constexpr float LAM_0   = 1000.0f * 0.2f / (1.2f * 0.6f);     // E nu/((1+nu)(1-2nu))
constexpr float GRAV    = 50.0f;

__device__ __forceinline__ int bin_of(float px, float py) {
    int bx = (int)floorf(px * INV_DX - 0.5f);
    int by = (int)floorf(py * INV_DX - 0.5f);
    bx = min(max(bx, 0), NG - 1);
    by = min(max(by, 0), NG - 1);
    return (bx << 8) | by;
}

// quadratic B-spline weight as a function of (node - particle) distance in cells
__device__ __forceinline__ float bw(float t) {
    float at = fabsf(t);
    float a  = fmaxf(1.5f - at, 0.0f);
    float w1 = 0.75f - t * t;
    float w2 = 0.5f * a * a;
    return (at < 0.5f) ? w1 : w2;
}

__device__ __forceinline__ void nt_store4(float4* dst, float a, float b, float c, float d) {
    vfloat4 val = { a, b, c, d };
    __builtin_nontemporal_store(val, reinterpret_cast<vfloat4*>(dst));
}

// ---------------- binning + scan ----------------

__global__ __launch_bounds__(256) void binrank_kernel(
    const float* __restrict__ x, int* __restrict__ counts, int* __restrict__ rank, int n)
{
    int i = blockIdx.x * blockDim.x + threadIdx.x;
    if (i >= n) return;
    float2 p = ((const float2*)x)[i];
    int b = bin_of(p.x, p.y);
    rank[i] = atomicAdd(&counts[b], 1);
}

__global__ __launch_bounds__(256) void scan1_kernel(
    const int* __restrict__ counts, int* __restrict__ starts, int* __restrict__ bsum)
{
    __shared__ int tmp[256];
    int t = threadIdx.x, b = blockIdx.x;
    int v = counts[b * 256 + t];
    tmp[t] = v;
    __syncthreads();
    #pragma unroll
    for (int off = 1; off < 256; off <<= 1) {
        int add = (t >= off) ? tmp[t - off] : 0;
        __syncthreads();
        tmp[t] += add;
        __syncthreads();
    }
    starts[b * 256 + t] = tmp[t] - v;          // exclusive within block
    if (t == 255) bsum[b] = tmp[255];          // block total
}

__global__ __launch_bounds__(256) void scan2_kernel(int* __restrict__ bsum)
{
    __shared__ int tmp[256];
    int t = threadIdx.x;
    int v = bsum[t];
    tmp[t] = v;
    __syncthreads();
    #pragma unroll
    for (int off = 1; off < 256; off <<= 1) {
        int add = (t >= off) ? tmp[t - off] : 0;
        __syncthreads();
        tmp[t] += add;
        __syncthreads();
    }
    bsum[t] = tmp[t] - v;                      // exclusive
}

__global__ __launch_bounds__(256) void scan3_kernel(
    int* __restrict__ starts, const int* __restrict__ bsum, int n)
{
    int i = blockIdx.x * blockDim.x + threadIdx.x;
    if (i < NG2) starts[i] += bsum[i >> 8];
    if (i == 0) starts[NG2] = n;
}

// ---------------- particle update + sorted interleaved record scatter ----------------

__global__ __launch_bounds__(256) void compute_scatter_kernel(
    const float* __restrict__ x, const float* __restrict__ v,
    const float* __restrict__ C, const float* __restrict__ F,
    const int* __restrict__ mat, const float* __restrict__ Jp,
    const int* __restrict__ starts, const int* __restrict__ rank,
    float4* __restrict__ srec,          // interleaved: srec[2k] = pos/b, srec[2k+1] = A
    float4* __restrict__ F_out4, float* __restrict__ mat_out, float* __restrict__ Jp_out,
    int n)
{
    int i = blockIdx.x * blockDim.x + threadIdx.x;
    if (i >= n) return;

    float2 xp = ((const float2*)x)[i];
    float2 vp = ((const float2*)v)[i];
    float4 Cp = ((const float4*)C)[i];
    float4 Fp = ((const float4*)F)[i];
    int    m  = mat[i];
    float  jp = Jp[i];

    float px = xp.x, py = xp.y;
    float C00 = Cp.x, C01 = Cp.y, C10 = Cp.z, C11 = Cp.w;
    float a = Fp.x, b = Fp.y, c = Fp.z, d = Fp.w;

    // F += dt * C @ F
    float na = a + DT*(C00*a + C01*c);
    float nb = b + DT*(C00*b + C01*d);
    float nc = c + DT*(C10*a + C11*c);
    float nd = d + DT*(C10*b + C11*d);
    a = na; b = nb; c = nc; d = nd;

    float h = expf(10.0f * (1.0f - jp));
    if (m == 1) h = 0.3f;
    float mu  = (m == 0) ? 0.0f : MU_0 * h;
    float lam = LAM_0 * h;

    // closed-form 2x2 SVD via eigendecomposition of A^T A
    float S00 = a*a + c*c, S01 = a*b + c*d, S11 = b*b + d*d;
    float mh = 0.5f*(S00 + S11), dh = 0.5f*(S00 - S11);
    float delta = sqrtf(dh*dh + S01*S01);
    float sig1 = sqrtf(fmaxf(mh + delta, 0.0f));
    float sig2 = sqrtf(fmaxf(mh - delta, 0.0f));
    float e0, e1;
    if (dh >= 0.0f) { e0 = delta + dh; e1 = S01; }
    else            { e0 = S01;        e1 = delta - dh; }
    float elen = sqrtf(e0*e0 + e1*e1);
    float vc, vs;
    if (elen > 1e-30f) { float il = 1.0f/elen; vc = e0*il; vs = e1*il; }
    else               { vc = 1.0f; vs = 0.0f; }
    float inv1 = 1.0f / fmaxf(sig1, 1e-30f);
    float inv2 = 1.0f / fmaxf(sig2, 1e-30f);
    float u1x = ( a*vc + b*vs) * inv1, u1y = ( c*vc + d*vs) * inv1;
    float u2x = (-a*vs + b*vc) * inv2, u2y = (-c*vs + d*vc) * inv2;

    if (m == 2) {   // snow plasticity
        float c1 = fminf(fmaxf(sig1, 1.0f - 2.5e-2f), 1.0f + 4.5e-3f);
        float c2 = fminf(fmaxf(sig2, 1.0f - 2.5e-2f), 1.0f + 4.5e-3f);
        jp = jp * (sig1 / c1) * (sig2 / c2);
        sig1 = c1; sig2 = c2;
    }
    float J = sig1 * sig2;

    if (m == 0) {              // fluid: F = sqrt(J) I
        float s = sqrtf(J);
        a = s; b = 0.0f; c = 0.0f; d = s;
    } else if (m == 2) {       // snow: F = U diag(sig) Vh
        a = sig1*u1x*vc - sig2*u2x*vs;
        b = sig1*u1x*vs + sig2*u2x*vc;
        c = sig1*u1y*vc - sig2*u2y*vs;
        d = sig1*u1y*vs + sig2*u2y*vc;
    }
    float R00 = u1x*vc - u2x*vs, R01 = u1x*vs + u2x*vc;
    float R10 = u1y*vc - u2y*vs, R11 = u1y*vs + u2y*vc;

    float k2mu = 2.0f * mu;
    float fr00 = a - R00, fr01 = b - R01, fr10 = c - R10, fr11 = d - R11;
    float ljj  = lam * J * (J - 1.0f);
    float st00 = k2mu*(fr00*a + fr01*b) + ljj;
    float st01 = k2mu*(fr00*c + fr01*d);
    float st10 = k2mu*(fr10*a + fr11*b);
    float st11 = k2mu*(fr10*c + fr11*d) + ljj;
    const float coef = -DT * P_VOL * 4.0f * INV_DX * INV_DX;
    float A00 = coef*st00 + P_MASS*C00;
    float A01 = coef*st01 + P_MASS*C01;
    float A10 = coef*st10 + P_MASS*C10;
    float A11 = coef*st11 + P_MASS*C11;

    float bx_ = P_MASS*vp.x - (A00*px + A01*py);
    float by_ = P_MASS*vp.y - (A10*px + A11*py);

    // interleaved 32B record at sorted slot: both halves hit the same 64B line
    int sidx = starts[bin_of(px, py)] + rank[i];
    nt_store4(&srec[2*sidx],     px * INV_DX, py * INV_DX, bx_, by_);
    nt_store4(&srec[2*sidx + 1], A00, A01, A10, A11);

    nt_store4(&F_out4[i], a, b, c, d);
    __builtin_nontemporal_store((float)m, &mat_out[i]);
    __builtin_nontemporal_store(jp, &Jp_out[i]);
}

// 16 threads per grid cell: gather from 3 contiguous sorted ranges (strided by
// slice), shuffle-reduce within the 16-lane group, fuse grid ops. XCD-swizzled
// blocks keep bin-row records L2-local.
__global__ __launch_bounds__(256) void gather_grid_kernel(
    const float4* __restrict__ srec, const int* __restrict__ starts,
    float2* __restrict__ gv)
{
    // bijective XCD swizzle: nwg = NG2*16/256 = 4096, 4096 % 8 == 0
    int bid  = blockIdx.x;
    int swz  = (bid & 7) * (4096 / 8) + (bid >> 3);
    int gtid  = swz * 256 + threadIdx.x;
    int cell  = gtid >> 4;
    int slice = gtid & 15;
    int gi = cell >> 8, gj = cell & (NG - 1);

    float fgi = (float)gi, fgj = (float)gj;
    float posx = fgi * DX, posy = fgj * DX;
    float msum = 0.0f, mvx = 0.0f, mvy = 0.0f;

    int j0 = max(gj - 2, 0);

    // prefetch all 6 range bounds (up to 3 bin rows)
    int sArr[3], eArr[3];
    #pragma unroll
    for (int t3 = 0; t3 < 3; ++t3) {
        int bi = gi - 2 + t3;
        bool valid = (bi >= 0);
        int row = (valid ? bi : 0) << 8;
        sArr[t3] = valid ? starts[row + j0] : 0;
        eArr[t3] = valid ? starts[row + gj + 1] : 0;
    }

    #pragma unroll
    for (int t3 = 0; t3 < 3; ++t3) {
        int s = sArr[t3], e = eArr[t3];
        for (int k = s + slice; k < e; k += 16) {
            float4 r0 = srec[2*k];
            float4 r1 = srec[2*k + 1];
            float w = bw(r0.x - fgi) * bw(r0.y - fgj);
            msum += w;
            mvx  += w * (r0.z + r1.x * posx + r1.y * posy);
            mvy  += w * (r0.w + r1.z * posx + r1.w * posy);
        }
    }

    // reduce across the 16 slices (lanes differing in bits 0..3 of lane id)
    #pragma unroll
    for (int off = 1; off < 16; off <<= 1) {
        msum += __shfl_xor(msum, off);
        mvx  += __shfl_xor(mvx,  off);
        mvy  += __shfl_xor(mvy,  off);
    }

    if (slice == 0) {
        float mass = msum * P_MASS;
        float vx = mvx, vy = mvy;
        if (mass > 0.0f) {
            float im = 1.0f / fmaxf(mass, 1e-12f);
            vx *= im; vy *= im;
        }
        vy -= DT * GRAV;
        if (gi < 3)      vx = fmaxf(vx, 0.0f);
        if (gi >= NG-2)  vx = fminf(vx, 0.0f);
        if (gj < 3)      vy = fmaxf(vy, 0.0f);
        if (gj >= NG-2)  vy = fminf(vy, 0.0f);
        gv[cell] = make_float2(vx, vy);
    }
}

__global__ __launch_bounds__(256) void g2p_kernel(
    const float* __restrict__ x, const float2* __restrict__ gv,
    float* __restrict__ x_out, float* __restrict__ v_out, float* __restrict__ C_out,
    int n)
{
    int i = blockIdx.x * blockDim.x + threadIdx.x;
    if (i >= n) return;

    float2 xp = ((const float2*)x)[i];
    float px = xp.x, py = xp.y;
    float bxf = floorf(px * INV_DX - 0.5f), byf = floorf(py * INV_DX - 0.5f);
    float fx = px * INV_DX - bxf, fy = py * INV_DX - byf;
    float wxs[3] = { 0.5f*(1.5f-fx)*(1.5f-fx), 0.75f-(fx-1.0f)*(fx-1.0f), 0.5f*(fx-0.5f)*(fx-0.5f) };
    float wys[3] = { 0.5f*(1.5f-fy)*(1.5f-fy), 0.75f-(fy-1.0f)*(fy-1.0f), 0.5f*(fy-0.5f)*(fy-0.5f) };
    int bix = (int)bxf, biy = (int)byf;

    float nvx = 0.0f, nvy = 0.0f;
    float c00 = 0.0f, c01 = 0.0f, c10 = 0.0f, c11 = 0.0f;
    #pragma unroll
    for (int ii = 0; ii < 3; ++ii) {
        float posx = (bxf + (float)ii) * DX;
        int rowbase = (bix + ii) * NG + biy;
        #pragma unroll
        for (int jj = 0; jj < 3; ++jj) {
            float w = wxs[ii] * wys[jj];
            float posy = (byf + (float)jj) * DX;
            float2 g = gv[rowbase + jj];
            nvx += w * g.x; nvy += w * g.y;
            c00 += w * g.x * posx; c01 += w * g.x * posy;
            c10 += w * g.y * posx; c11 += w * g.y * posy;
        }
    }
    const float K = 4.0f * INV_DX * INV_DX;
    c00 = (c00 - nvx * px) * K; c01 = (c01 - nvx * py) * K;
    c10 = (c10 - nvy * px) * K; c11 = (c11 - nvy * py) * K;

    ((float2*)x_out)[i] = make_float2(px + DT * nvx, py + DT * nvy);
    ((float2*)v_out)[i] = make_float2(nvx, nvy);
    ((float4*)C_out)[i] = make_float4(c00, c01, c10, c11);
}

extern "C" void kernel_launch(void* const* d_in, const int* in_sizes, int n_in,
                              void* d_out, int out_size, void* d_ws, size_t ws_size,
                              hipStream_t stream) {
    const float* x   = (const float*)d_in[0];
    const float* v   = (const float*)d_in[1];
    const float* C   = (const float*)d_in[2];
    const float* F   = (const float*)d_in[3];
    const int*   mat = (const int*)d_in[4];
    const float* Jp  = (const float*)d_in[5];

    int n = in_sizes[0] / 2;

    float* out     = (float*)d_out;
    float* x_out   = out;
    float* v_out   = out + (size_t)2*n;
    float* C_out   = out + (size_t)4*n;
    float* F_out   = out + (size_t)8*n;
    float* mat_out = out + (size_t)12*n;
    float* Jp_out  = out + (size_t)13*n;

    int blocks = (n + 255) / 256;

    // workspace layout
    char* ws = (char*)d_ws;
    size_t off = 0;
    int* counts = (int*)(ws + off); off += (size_t)NG2 * 4;
    int* starts = (int*)(ws + off); off += (size_t)(NG2 + 1) * 4;
    int* bsum   = (int*)(ws + off); off += 256 * 4;
    int* rank   = (int*)(ws + off); off += (size_t)n * 4;
    off = (off + 63) & ~(size_t)63;          // 64B align records
    float4* srec = (float4*)(ws + off); off += (size_t)n * 32;
    float2* gv   = (float2*)(ws + off); off += (size_t)NG2 * 8;

    hipMemsetAsync(counts, 0, (size_t)NG2 * 4, stream);
    binrank_kernel<<<blocks, 256, 0, stream>>>(x, counts, rank, n);
    scan1_kernel<<<NG2/256, 256, 0, stream>>>(counts, starts, bsum);
    scan2_kernel<<<1, 256, 0, stream>>>(bsum);
    scan3_kernel<<<NG2/256, 256, 0, stream>>>(starts, bsum, n);
    compute_scatter_kernel<<<blocks, 256, 0, stream>>>(x, v, C, F, mat, Jp,
                                                       starts, rank, srec,
                                                       (float4*)F_out, mat_out, Jp_out, n);
    gather_grid_kernel<<<(NG2*16)/256, 256, 0, stream>>>(srec, starts, gv);
    g2p_kernel<<<blocks, 256, 0, stream>>>(x, gv, x_out, v_out, C_out, n);
}

// Round 9
// 130.006 us; speedup vs baseline: 1.3865x; 1.3819x over previous
//
#include <hip/hip_runtime.h>

#define NG 256
#define NG2 (NG*NG)

constexpr float DX      = 1.0f / 256.0f;
constexpr float INV_DX  = 256.0f;
constexpr float DT      = 2e-5f;
constexpr float P_VOL   = (1.0f/512.0f) * (1.0f/512.0f);
constexpr float P_MASS  = P_VOL;           // rho = 1
constexpr float MU_0    = 1000.0f / (2.0f * 1.2f);            // E/(2(1+nu))
constexpr float LAM_0   = 1000.0f * 0.2f / (1.2f * 0.6f);     // E nu/((1+nu)(1-2nu))
constexpr float GRAV    = 50.0f;

__device__ __forceinline__ int bin_of(float px, float py) {
    int bx = (int)floorf(px * INV_DX - 0.5f);
    int by = (int)floorf(py * INV_DX - 0.5f);
    bx = min(max(bx, 0), NG - 1);
    by = min(max(by, 0), NG - 1);
    return (bx << 8) | by;
}

// quadratic B-spline weight as a function of (node - particle) distance in cells
__device__ __forceinline__ float bw(float t) {
    float at = fabsf(t);
    float a  = fmaxf(1.5f - at, 0.0f);
    float w1 = 0.75f - t * t;
    float w2 = 0.5f * a * a;
    return (at < 0.5f) ? w1 : w2;
}

// ---------------- binning + scan ----------------

__global__ __launch_bounds__(256) void binrank_kernel(
    const float* __restrict__ x, int* __restrict__ counts, int* __restrict__ rank, int n)
{
    int i = blockIdx.x * blockDim.x + threadIdx.x;
    if (i >= n) return;
    float2 p = ((const float2*)x)[i];
    int b = bin_of(p.x, p.y);
    rank[i] = atomicAdd(&counts[b], 1);
}

__global__ __launch_bounds__(256) void scan1_kernel(
    const int* __restrict__ counts, int* __restrict__ starts, int* __restrict__ bsum)
{
    __shared__ int tmp[256];
    int t = threadIdx.x, b = blockIdx.x;
    int v = counts[b * 256 + t];
    tmp[t] = v;
    __syncthreads();
    #pragma unroll
    for (int off = 1; off < 256; off <<= 1) {
        int add = (t >= off) ? tmp[t - off] : 0;
        __syncthreads();
        tmp[t] += add;
        __syncthreads();
    }
    starts[b * 256 + t] = tmp[t] - v;          // exclusive within block
    if (t == 255) bsum[b] = tmp[255];          // block total
}

__global__ __launch_bounds__(256) void scan2_kernel(int* __restrict__ bsum)
{
    __shared__ int tmp[256];
    int t = threadIdx.x;
    int v = bsum[t];
    tmp[t] = v;
    __syncthreads();
    #pragma unroll
    for (int off = 1; off < 256; off <<= 1) {
        int add = (t >= off) ? tmp[t - off] : 0;
        __syncthreads();
        tmp[t] += add;
        __syncthreads();
    }
    bsum[t] = tmp[t] - v;                      // exclusive
}

__global__ __launch_bounds__(256) void scan3_kernel(
    int* __restrict__ starts, const int* __restrict__ bsum, int n)
{
    int i = blockIdx.x * blockDim.x + threadIdx.x;
    if (i < NG2) starts[i] += bsum[i >> 8];
    if (i == 0) starts[NG2] = n;
}

// ---------------- particle update + sorted interleaved record scatter ----------------

__global__ __launch_bounds__(256) void compute_scatter_kernel(
    const float* __restrict__ x, const float* __restrict__ v,
    const float* __restrict__ C, const float* __restrict__ F,
    const int* __restrict__ mat, const float* __restrict__ Jp,
    const int* __restrict__ starts, const int* __restrict__ rank,
    float4* __restrict__ srec,          // interleaved: srec[2k] = pos/b, srec[2k+1] = A
    float4* __restrict__ F_out4, float* __restrict__ mat_out, float* __restrict__ Jp_out,
    int n)
{
    int i = blockIdx.x * blockDim.x + threadIdx.x;
    if (i >= n) return;

    float2 xp = ((const float2*)x)[i];
    float2 vp = ((const float2*)v)[i];
    float4 Cp = ((const float4*)C)[i];
    float4 Fp = ((const float4*)F)[i];
    int    m  = mat[i];
    float  jp = Jp[i];

    float px = xp.x, py = xp.y;
    float C00 = Cp.x, C01 = Cp.y, C10 = Cp.z, C11 = Cp.w;
    float a = Fp.x, b = Fp.y, c = Fp.z, d = Fp.w;

    // F += dt * C @ F
    float na = a + DT*(C00*a + C01*c);
    float nb = b + DT*(C00*b + C01*d);
    float nc = c + DT*(C10*a + C11*c);
    float nd = d + DT*(C10*b + C11*d);
    a = na; b = nb; c = nc; d = nd;

    float h = expf(10.0f * (1.0f - jp));
    if (m == 1) h = 0.3f;
    float mu  = (m == 0) ? 0.0f : MU_0 * h;
    float lam = LAM_0 * h;

    // closed-form 2x2 SVD via eigendecomposition of A^T A
    float S00 = a*a + c*c, S01 = a*b + c*d, S11 = b*b + d*d;
    float mh = 0.5f*(S00 + S11), dh = 0.5f*(S00 - S11);
    float delta = sqrtf(dh*dh + S01*S01);
    float sig1 = sqrtf(fmaxf(mh + delta, 0.0f));
    float sig2 = sqrtf(fmaxf(mh - delta, 0.0f));
    float e0, e1;
    if (dh >= 0.0f) { e0 = delta + dh; e1 = S01; }
    else            { e0 = S01;        e1 = delta - dh; }
    float elen = sqrtf(e0*e0 + e1*e1);
    float vc, vs;
    if (elen > 1e-30f) { float il = 1.0f/elen; vc = e0*il; vs = e1*il; }
    else               { vc = 1.0f; vs = 0.0f; }
    float inv1 = 1.0f / fmaxf(sig1, 1e-30f);
    float inv2 = 1.0f / fmaxf(sig2, 1e-30f);
    float u1x = ( a*vc + b*vs) * inv1, u1y = ( c*vc + d*vs) * inv1;
    float u2x = (-a*vs + b*vc) * inv2, u2y = (-c*vs + d*vc) * inv2;

    if (m == 2) {   // snow plasticity
        float c1 = fminf(fmaxf(sig1, 1.0f - 2.5e-2f), 1.0f + 4.5e-3f);
        float c2 = fminf(fmaxf(sig2, 1.0f - 2.5e-2f), 1.0f + 4.5e-3f);
        jp = jp * (sig1 / c1) * (sig2 / c2);
        sig1 = c1; sig2 = c2;
    }
    float J = sig1 * sig2;

    if (m == 0) {              // fluid: F = sqrt(J) I
        float s = sqrtf(J);
        a = s; b = 0.0f; c = 0.0f; d = s;
    } else if (m == 2) {       // snow: F = U diag(sig) Vh
        a = sig1*u1x*vc - sig2*u2x*vs;
        b = sig1*u1x*vs + sig2*u2x*vc;
        c = sig1*u1y*vc - sig2*u2y*vs;
        d = sig1*u1y*vs + sig2*u2y*vc;
    }
    float R00 = u1x*vc - u2x*vs, R01 = u1x*vs + u2x*vc;
    float R10 = u1y*vc - u2y*vs, R11 = u1y*vs + u2y*vc;

    float k2mu = 2.0f * mu;
    float fr00 = a - R00, fr01 = b - R01, fr10 = c - R10, fr11 = d - R11;
    float ljj  = lam * J * (J - 1.0f);
    float st00 = k2mu*(fr00*a + fr01*b) + ljj;
    float st01 = k2mu*(fr00*c + fr01*d);
    float st10 = k2mu*(fr10*a + fr11*b);
    float st11 = k2mu*(fr10*c + fr11*d) + ljj;
    const float coef = -DT * P_VOL * 4.0f * INV_DX * INV_DX;
    float A00 = coef*st00 + P_MASS*C00;
    float A01 = coef*st01 + P_MASS*C01;
    float A10 = coef*st10 + P_MASS*C10;
    float A11 = coef*st11 + P_MASS*C11;

    float bx_ = P_MASS*vp.x - (A00*px + A01*py);
    float by_ = P_MASS*vp.y - (A10*px + A11*py);

    // interleaved 32B record at sorted slot: both halves hit the same 64B line
    int sidx = starts[bin_of(px, py)] + rank[i];
    srec[2*sidx]     = make_float4(px * INV_DX, py * INV_DX, bx_, by_);
    srec[2*sidx + 1] = make_float4(A00, A01, A10, A11);

    F_out4[i]  = make_float4(a, b, c, d);
    mat_out[i] = (float)m;
    Jp_out[i]  = jp;
}

// 16 threads per grid cell: gather from 3 contiguous sorted ranges (strided by
// slice), shuffle-reduce within the 16-lane group, fuse grid ops. XCD-swizzled
// blocks keep bin-row records L2-local.
__global__ __launch_bounds__(256) void gather_grid_kernel(
    const float4* __restrict__ srec, const int* __restrict__ starts,
    float2* __restrict__ gv)
{
    // bijective XCD swizzle: nwg = NG2*16/256 = 4096, 4096 % 8 == 0
    int bid  = blockIdx.x;
    int swz  = (bid & 7) * (4096 / 8) + (bid >> 3);
    int gtid  = swz * 256 + threadIdx.x;
    int cell  = gtid >> 4;
    int slice = gtid & 15;
    int gi = cell >> 8, gj = cell & (NG - 1);

    float fgi = (float)gi, fgj = (float)gj;
    float posx = fgi * DX, posy = fgj * DX;
    float msum = 0.0f, mvx = 0.0f, mvy = 0.0f;

    int j0 = max(gj - 2, 0);

    // prefetch all 6 range bounds (up to 3 bin rows)
    int sArr[3], eArr[3];
    #pragma unroll
    for (int t3 = 0; t3 < 3; ++t3) {
        int bi = gi - 2 + t3;
        bool valid = (bi >= 0);
        int row = (valid ? bi : 0) << 8;
        sArr[t3] = valid ? starts[row + j0] : 0;
        eArr[t3] = valid ? starts[row + gj + 1] : 0;
    }

    #pragma unroll
    for (int t3 = 0; t3 < 3; ++t3) {
        int s = sArr[t3], e = eArr[t3];
        for (int k = s + slice; k < e; k += 16) {
            float4 r0 = srec[2*k];
            float4 r1 = srec[2*k + 1];
            float w = bw(r0.x - fgi) * bw(r0.y - fgj);
            msum += w;
            mvx  += w * (r0.z + r1.x * posx + r1.y * posy);
            mvy  += w * (r0.w + r1.z * posx + r1.w * posy);
        }
    }

    // reduce across the 16 slices (lanes differing in bits 0..3 of lane id)
    #pragma unroll
    for (int off = 1; off < 16; off <<= 1) {
        msum += __shfl_xor(msum, off);
        mvx  += __shfl_xor(mvx,  off);
        mvy  += __shfl_xor(mvy,  off);
    }

    if (slice == 0) {
        float mass = msum * P_MASS;
        float vx = mvx, vy = mvy;
        if (mass > 0.0f) {
            float im = 1.0f / fmaxf(mass, 1e-12f);
            vx *= im; vy *= im;
        }
        vy -= DT * GRAV;
        if (gi < 3)      vx = fmaxf(vx, 0.0f);
        if (gi >= NG-2)  vx = fminf(vx, 0.0f);
        if (gj < 3)      vy = fmaxf(vy, 0.0f);
        if (gj >= NG-2)  vy = fminf(vy, 0.0f);
        gv[cell] = make_float2(vx, vy);
    }
}

__global__ __launch_bounds__(256) void g2p_kernel(
    const float* __restrict__ x, const float2* __restrict__ gv,
    float* __restrict__ x_out, float* __restrict__ v_out, float* __restrict__ C_out,
    int n)
{
    int i = blockIdx.x * blockDim.x + threadIdx.x;
    if (i >= n) return;

    float2 xp = ((const float2*)x)[i];
    float px = xp.x, py = xp.y;
    float bxf = floorf(px * INV_DX - 0.5f), byf = floorf(py * INV_DX - 0.5f);
    float fx = px * INV_DX - bxf, fy = py * INV_DX - byf;
    float wxs[3] = { 0.5f*(1.5f-fx)*(1.5f-fx), 0.75f-(fx-1.0f)*(fx-1.0f), 0.5f*(fx-0.5f)*(fx-0.5f) };
    float wys[3] = { 0.5f*(1.5f-fy)*(1.5f-fy), 0.75f-(fy-1.0f)*(fy-1.0f), 0.5f*(fy-0.5f)*(fy-0.5f) };
    int bix = (int)bxf, biy = (int)byf;

    float nvx = 0.0f, nvy = 0.0f;
    float c00 = 0.0f, c01 = 0.0f, c10 = 0.0f, c11 = 0.0f;
    #pragma unroll
    for (int ii = 0; ii < 3; ++ii) {
        float posx = (bxf + (float)ii) * DX;
        int rowbase = (bix + ii) * NG + biy;
        #pragma unroll
        for (int jj = 0; jj < 3; ++jj) {
            float w = wxs[ii] * wys[jj];
            float posy = (byf + (float)jj) * DX;
            float2 g = gv[rowbase + jj];
            nvx += w * g.x; nvy += w * g.y;
            c00 += w * g.x * posx; c01 += w * g.x * posy;
            c10 += w * g.y * posx; c11 += w * g.y * posy;
        }
    }
    const float K = 4.0f * INV_DX * INV_DX;
    c00 = (c00 - nvx * px) * K; c01 = (c01 - nvx * py) * K;
    c10 = (c10 - nvy * px) * K; c11 = (c11 - nvy * py) * K;

    ((float2*)x_out)[i] = make_float2(px + DT * nvx, py + DT * nvy);
    ((float2*)v_out)[i] = make_float2(nvx, nvy);
    ((float4*)C_out)[i] = make_float4(c00, c01, c10, c11);
}

extern "C" void kernel_launch(void* const* d_in, const int* in_sizes, int n_in,
                              void* d_out, int out_size, void* d_ws, size_t ws_size,
                              hipStream_t stream) {
    const float* x   = (const float*)d_in[0];
    const float* v   = (const float*)d_in[1];
    const float* C   = (const float*)d_in[2];
    const float* F   = (const float*)d_in[3];
    const int*   mat = (const int*)d_in[4];
    const float* Jp  = (const float*)d_in[5];

    int n = in_sizes[0] / 2;

    float* out     = (float*)d_out;
    float* x_out   = out;
    float* v_out   = out + (size_t)2*n;
    float* C_out   = out + (size_t)4*n;
    float* F_out   = out + (size_t)8*n;
    float* mat_out = out + (size_t)12*n;
    float* Jp_out  = out + (size_t)13*n;

    int blocks = (n + 255) / 256;

    // workspace layout
    char* ws = (char*)d_ws;
    size_t off = 0;
    int* counts = (int*)(ws + off); off += (size_t)NG2 * 4;
    int* starts = (int*)(ws + off); off += (size_t)(NG2 + 1) * 4;
    int* bsum   = (int*)(ws + off); off += 256 * 4;
    int* rank   = (int*)(ws + off); off += (size_t)n * 4;
    off = (off + 63) & ~(size_t)63;          // 64B align records
    float4* srec = (float4*)(ws + off); off += (size_t)n * 32;
    float2* gv   = (float2*)(ws + off); off += (size_t)NG2 * 8;

    hipMemsetAsync(counts, 0, (size_t)NG2 * 4, stream);
    binrank_kernel<<<blocks, 256, 0, stream>>>(x, counts, rank, n);
    scan1_kernel<<<NG2/256, 256, 0, stream>>>(counts, starts, bsum);
    scan2_kernel<<<1, 256, 0, stream>>>(bsum);
    scan3_kernel<<<NG2/256, 256, 0, stream>>>(starts, bsum, n);
    compute_scatter_kernel<<<blocks, 256, 0, stream>>>(x, v, C, F, mat, Jp,
                                                       starts, rank, srec,
                                                       (float4*)F_out, mat_out, Jp_out, n);
    gather_grid_kernel<<<(NG2*16)/256, 256, 0, stream>>>(srec, starts, gv);
    g2p_kernel<<<blocks, 256, 0, stream>>>(x, gv, x_out, v_out, C_out, n);
}